// Round 5
// baseline (953.597 us; speedup 1.0000x reference)
//
#include <hip/hip_runtime.h>
#include <hip/hip_bf16.h>
#include <stdint.h>

#define B_ 128
#define N_ 512
#define S_ 8
#define H_ 64
#define M_ (B_*N_)          // 65536 rows
#define L2E 1.442695041f

typedef __attribute__((ext_vector_type(8))) short bf16x8;
typedef __attribute__((ext_vector_type(4))) float f32x4;

__device__ __forceinline__ float exp2f_(float x) { return __builtin_amdgcn_exp2f(x); }
// x pre-scaled by log2(e):  sig2(x) == sigmoid(x / L2E)
__device__ __forceinline__ float sig2(float x)  { return 1.f / (1.f + exp2f_(-x)); }
// x pre-scaled by 2*log2(e): tanh2(x) == tanh(x / (2*L2E))
__device__ __forceinline__ float tanh2(float x) { return 1.f - 2.f / (exp2f_(x) + 1.f); }
__device__ __forceinline__ float dot4(float4 a, float4 b) {
  return a.x*b.x + a.y*b.y + a.z*b.z + a.w*b.w;
}
// fp32 -> bf16 round-to-nearest-even
__device__ __forceinline__ unsigned short f2bf(float x) {
  unsigned int u = __float_as_uint(x);
  u += 0x7fffu + ((u >> 16) & 1u);
  return (unsigned short)(u >> 16);
}

// ---------------------------------------------------------------------------
// pad_mask (B,N,N) -> bitmask, 1 bit per (q,key).
__global__ __launch_bounds__(256) void maskpack_kernel(
    const int* __restrict__ pm, uint32_t* __restrict__ bm, int n)
{
  int g = blockIdx.x * 256 + threadIdx.x;
  if (g >= n) return;
  unsigned long long ball = __ballot(pm[g] != 0);
  int lane = threadIdx.x & 63;
  if (lane == 0)       bm[g >> 5] = (uint32_t)ball;
  else if (lane == 32) bm[g >> 5] = (uint32_t)(ball >> 32);
}

// ---------------------------------------------------------------------------
// MFMA LSTM v3. 512 threads = 8 waves; 128 rows/block (16 rows/wave).
// grid = 512 = exactly 2 blocks/CU -> 16 waves/CU, no tail round.
// Waves are fully independent in the step loop (each touches only its own 16
// h_s rows) -> NO per-step barrier. h stored bf16 (consumed only by bf16 MFMA
// and bf16 he output); c stays fp32 in VGPRs (C-layout).
__global__ __launch_bounds__(512, 4) void lstm_kernel(
    const float* __restrict__ obs, const float* __restrict__ nhm,
    const float* __restrict__ Wih, const float* __restrict__ Whh,
    const float* __restrict__ bih, const float* __restrict__ bhh,
    unsigned short* __restrict__ he)
{
  __shared__ short Wfrag[32*512];      // 32 KB   B-frags of Whh (bf16)
  __shared__ short h_s[128*72];        // 18 KB   bf16, stride 72 (b128-aligned)
  __shared__ float x_s[128][18];       // 9.2 KB
  __shared__ int   len_s[128];

  const int tid  = threadIdx.x;
  const int lane = tid & 63;
  const int wv   = tid >> 6;           // 0..7
  const int w16  = wv * 16;
  const int quad = lane >> 4;
  const int col  = lane & 15;
  const int row0 = blockIdx.x * 128;

  // stage Whh as bf16 B-fragments, pre-scaled per gate type
  #pragma unroll
  for (int i = 0; i < 4; ++i) {
    int p = i*512 + tid;               // 2048 (frag,lane) entries
    int f = p >> 6, l = p & 63;
    int t16 = f >> 1, s = f & 1;
    int lq = l >> 4, lc = l & 15;
    const float sc = (t16 >= 8 && t16 < 12) ? (2.f*L2E) : L2E;
    const float* src = Whh + (size_t)(t16*16 + lc)*64 + s*32 + lq*8;
    short* dst = Wfrag + f*512 + l*8;
    #pragma unroll
    for (int j = 0; j < 8; ++j) dst[j] = (short)f2bf(src[j] * sc);
  }

  float bias_n[16], wi0[16], wi1[16];
  #pragma unroll
  for (int t16 = 0; t16 < 16; ++t16) {
    int n = t16*16 + col;
    const float sc = (t16 >= 8 && t16 < 12) ? (2.f*L2E) : L2E;
    bias_n[t16] = (bih[n] + bhh[n]) * sc;
    wi0[t16] = Wih[2*n + 0] * sc;
    wi1[t16] = Wih[2*n + 1] * sc;
  }

  // zero h (4608 dwords)
  #pragma unroll
  for (int i = 0; i < 9; ++i) ((uint32_t*)h_s)[i*512 + tid] = 0u;

  if (tid < 128) {
    int r = tid;
    float xv0[8], xv1[8];
    int lzi = -1;
    for (int t = 0; t < 8; ++t) {
      float m = nhm[(size_t)(row0+r)*8 + t];
      float a = obs[((size_t)(row0+r)*8 + t)*2 + 0] * m;
      float b = obs[((size_t)(row0+r)*8 + t)*2 + 1] * m;
      xv0[t] = a; xv1[t] = b;
      if (a == 0.f) lzi = t;
    }
    for (int t = 0; t < 8; ++t) {
      bool kill = (t < lzi);
      x_s[r][t*2+0] = kill ? 0.f : xv0[t];
      x_s[r][t*2+1] = kill ? 0.f : xv1[t];
    }
    int len = 7 - lzi; if (len < 1) len = 1;
    len_s[r] = len;
  }
  __syncthreads();     // the ONLY barrier: staging + init visible to all

  int lenr[4];
  #pragma unroll
  for (int r = 0; r < 4; ++r) lenr[r] = len_s[w16 + quad*4 + r];

  float c_[16];
  #pragma unroll
  for (int i = 0; i < 16; ++i) c_[i] = 0.f;

  for (int t = 0; t < 8; ++t) {
    float x0[4], x1[4];
    #pragma unroll
    for (int r = 0; r < 4; ++r) {
      x0[r] = x_s[w16 + quad*4 + r][t*2+0];
      x1[r] = x_s[w16 + quad*4 + r][t*2+1];
    }

    f32x4 acc[16];
    #pragma unroll
    for (int t16 = 0; t16 < 16; ++t16) {
      #pragma unroll
      for (int r = 0; r < 4; ++r)
        acc[t16][r] = bias_n[t16] + wi0[t16]*x0[r] + wi1[t16]*x1[r];
    }

    // A-frags straight from bf16 h_s (no converts)
    bf16x8 a0 = *(const bf16x8*)(h_s + (w16 + col)*72 + quad*8);
    bf16x8 a1 = *(const bf16x8*)(h_s + (w16 + col)*72 + 32 + quad*8);

    #pragma unroll
    for (int t16 = 0; t16 < 16; ++t16) {
      bf16x8 b0 = *(const bf16x8*)(Wfrag + (t16*2+0)*512 + lane*8);
      bf16x8 b1 = *(const bf16x8*)(Wfrag + (t16*2+1)*512 + lane*8);
      acc[t16] = __builtin_amdgcn_mfma_f32_16x16x32_bf16(a0, b0, acc[t16], 0, 0, 0);
      acc[t16] = __builtin_amdgcn_mfma_f32_16x16x32_bf16(a1, b1, acc[t16], 0, 0, 0);
    }

    #pragma unroll
    for (int tt = 0; tt < 4; ++tt) {
      #pragma unroll
      for (int r = 0; r < 4; ++r) {
        if (t < lenr[r]) {
          float gi = acc[tt   ][r];
          float gf = acc[tt+ 4][r];
          float gg = acc[tt+ 8][r];
          float go = acc[tt+12][r];
          float cn = sig2(gf)*c_[tt*4+r] + sig2(gi)*tanh2(gg);
          c_[tt*4+r] = cn;
          h_s[(w16 + quad*4 + r)*72 + tt*16 + col] =
              (short)f2bf(sig2(go)*tanh2(cn*(2.f*L2E)));
        }
      }
    }
    // no barrier: each wave owns its 16 rows; same-wave DS RAW is in-order
  }

  // he = relu(h) bf16, wave-local b128 stores
  #pragma unroll
  for (int s = 0; s < 2; ++s) {
    int chunk = s*64 + lane;          // 128 chunks of 8 shorts per wave
    int rl = chunk >> 3, c8 = chunk & 7;
    bf16x8 v = *(const bf16x8*)(h_s + (w16 + rl)*72 + c8*8);
    #pragma unroll
    for (int j = 0; j < 8; ++j) {
      short sv = v[j];
      v[j] = (sv & (short)0x8000) ? (short)0 : sv;   // relu (handles -0.0)
    }
    *(bf16x8*)(he + (size_t)(row0 + w16 + rl)*64 + c8*8) = v;
  }
}

// ---------------------------------------------------------------------------
// MFMA MLP: 3x relu(64x64) -> hidden -> q,k,v. 64 rows/block, 16 rows/wave.
// q,k bf16 row-major; v -> fp32 feat[:, :64] AND bf16 transposed vt[b][dim][key]
// (attn V^T staging becomes pure b128 copies). Wq/bq pre-scaled by log2(e).
__global__ __launch_bounds__(256) void mlp_kernel(
    const unsigned short* __restrict__ he,
    const float* __restrict__ W1, const float* __restrict__ b1,
    const float* __restrict__ W2, const float* __restrict__ b2,
    const float* __restrict__ Wh, const float* __restrict__ bh,
    const float* __restrict__ Wq, const float* __restrict__ bq,
    const float* __restrict__ Wk, const float* __restrict__ bk,
    const float* __restrict__ Wv, const float* __restrict__ bv,
    unsigned short* __restrict__ qb, unsigned short* __restrict__ kb,
    unsigned short* __restrict__ vt, float* __restrict__ feat)
{
  __shared__ short Wm[3][8*512];       // 24 KB B-frags
  __shared__ float bias_s[6*64];       // 1.5 KB
  __shared__ short Atile[4][16*76];    // 9.5 KB per-wave relayout tiles

  const int tid  = threadIdx.x;
  const int lane = tid & 63;
  const int wv   = tid >> 6;
  const int quad = lane >> 4;
  const int col  = lane & 15;
  const int rowb = blockIdx.x*64 + wv*16;

  const float* m1[3] = {W1, W2, Wh};
  const float* m2[3] = {Wq, Wk, Wv};
  auto stage3 = [&](const float* const* mats, float sc0) {
    #pragma unroll
    for (int i = 0; i < 6; ++i) {
      int p = i*256 + tid;
      int m = p >> 9, rem = p & 511;
      int f = rem >> 6, l = rem & 63;
      int nt = f >> 1, s = f & 1;
      int lq = l >> 4, lc = l & 15;
      float sc = (m == 0) ? sc0 : 1.f;
      const float* src = mats[m] + (size_t)(nt*16 + lc)*64 + s*32 + lq*8;
      short* dst = &Wm[m][f*512 + l*8];
      #pragma unroll
      for (int j = 0; j < 8; ++j) dst[j] = (short)f2bf(src[j] * sc);
    }
  };
  stage3(m1, 1.f);
  {
    const float* bs[6] = {b1, b2, bh, bq, bk, bv};
    for (int i = tid; i < 384; i += 256) {
      float sc = ((i >> 6) == 3) ? L2E : 1.f;      // bq scaled by log2(e)
      bias_s[i] = bs[i>>6][i & 63] * sc;
    }
  }
  __syncthreads();

  bf16x8 a0 = *(const bf16x8*)(he + (size_t)(rowb + col)*64 + quad*8);
  bf16x8 a1 = *(const bf16x8*)(he + (size_t)(rowb + col)*64 + quad*8 + 32);

  f32x4 acc[4];
  auto runL = [&](int m, int bidx) {
    #pragma unroll
    for (int nt = 0; nt < 4; ++nt) {
      float bb = bias_s[bidx*64 + nt*16 + col];
      acc[nt][0] = bb; acc[nt][1] = bb; acc[nt][2] = bb; acc[nt][3] = bb;
    }
    #pragma unroll
    for (int nt = 0; nt < 4; ++nt) {
      bf16x8 bf0 = *(const bf16x8*)(&Wm[m][(nt*2+0)*512 + lane*8]);
      bf16x8 bf1 = *(const bf16x8*)(&Wm[m][(nt*2+1)*512 + lane*8]);
      acc[nt] = __builtin_amdgcn_mfma_f32_16x16x32_bf16(a0, bf0, acc[nt], 0,0,0);
      acc[nt] = __builtin_amdgcn_mfma_f32_16x16x32_bf16(a1, bf1, acc[nt], 0,0,0);
    }
  };
  auto tileWrite = [&](bool relu) {
    #pragma unroll
    for (int nt = 0; nt < 4; ++nt)
      #pragma unroll
      for (int r = 0; r < 4; ++r) {
        float v = relu ? fmaxf(acc[nt][r], 0.f) : acc[nt][r];
        Atile[wv][(quad*4+r)*76 + ((nt*16+col) ^ (r*16))] = (short)f2bf(v);
      }
  };
  auto tileReadA = [&]() {
    int sw = (col & 3) * 16;
    a0 = *(const bf16x8*)(&Atile[wv][col*76 + ((quad*8     ) ^ sw)]);
    a1 = *(const bf16x8*)(&Atile[wv][col*76 + ((quad*8 + 32) ^ sw)]);
  };
  auto storeBF = [&](unsigned short* dst) {
    #pragma unroll
    for (int s = 0; s < 2; ++s) {
      int chunk = s*64 + lane;
      int r = chunk >> 3, c8 = chunk & 7;
      bf16x8 v = *(const bf16x8*)(&Atile[wv][r*76 + ((c8*8) ^ ((r&3)*16))]);
      *(bf16x8*)(dst + (size_t)(rowb + r)*64 + c8*8) = v;
    }
  };

  runL(0, 0); tileWrite(true); tileReadA();
  runL(1, 1); tileWrite(true); tileReadA();
  runL(2, 2); tileWrite(true); tileReadA();      // a0/a1 = hidden A-frags
  __syncthreads();
  stage3(m2, L2E);                               // Wq scaled by log2(e)
  __syncthreads();

  runL(0, 3); tileWrite(false); storeBF(qb);     // q (bf16, L2E-scaled)
  runL(1, 4); tileWrite(false); storeBF(kb);     // k (bf16)
  runL(2, 5);                                    // v
  {
    const int bi   = rowb >> 9;                  // batch
    const int key0 = (rowb & 511) + quad*4;
    #pragma unroll
    for (int nt = 0; nt < 4; ++nt) {
      #pragma unroll
      for (int r = 0; r < 4; ++r)
        feat[(size_t)(rowb + quad*4 + r)*128 + nt*16 + col] = acc[nt][r];
      uint32_t lo = (uint32_t)f2bf(acc[nt][0]) | ((uint32_t)f2bf(acc[nt][1]) << 16);
      uint32_t hi = (uint32_t)f2bf(acc[nt][2]) | ((uint32_t)f2bf(acc[nt][3]) << 16);
      uint2 pk; pk.x = lo; pk.y = hi;
      *(uint2*)(vt + ((size_t)bi*64 + nt*16 + col)*512 + key0) = pk;
    }
  }
}

// ---------------------------------------------------------------------------
// MFMA attention. q pre-scaled by log2(e); V^T staging = pure b128 copies.
__global__ __launch_bounds__(256) void attn_kernel(
    const unsigned short* __restrict__ qg, const unsigned short* __restrict__ kg,
    const unsigned short* __restrict__ vt,
    const uint32_t* __restrict__ bm, float* __restrict__ feat)
{
  __shared__ short    Ks[128*72];      // 18.0 KB
  __shared__ short    Vt[64*136];      // 17.0 KB
  __shared__ short    Pl[4][16*32];    // 4 KB, per-wave
  __shared__ uint32_t Ms[4][256];      // 4 KB, per-wave mask words

  const int tid  = threadIdx.x;
  const int lane = tid & 63;
  const int wv   = tid >> 6;
  const int quad = lane >> 4;
  const int col  = lane & 15;

  const int b     = blockIdx.x >> 3;
  const int q0    = (blockIdx.x & 7) * 64;
  const int qbase = b*512 + q0 + wv*16;

  bf16x8 qa[2];
  qa[0] = *(const bf16x8*)(qg + (size_t)(qbase + col)*64 + quad*8);
  qa[1] = *(const bf16x8*)(qg + (size_t)(qbase + col)*64 + quad*8 + 32);

  #pragma unroll
  for (int w = 0; w < 4; ++w)
    Ms[wv][w*64 + lane] = bm[(size_t)qbase*16 + w*64 + lane];

  f32x4 o_acc[4];
  #pragma unroll
  for (int nt = 0; nt < 4; ++nt)
    #pragma unroll
    for (int r = 0; r < 4; ++r) o_acc[nt][r] = 0.f;
  float l_part[4] = {0.f, 0.f, 0.f, 0.f};

  const unsigned short* vtb = vt + (size_t)b*64*512;

  for (int c = 0; c < 4; ++c) {
    __syncthreads();
    {
      const int kb_ = b*512 + c*128;
      // K chunk: bf16 [key][dim] stride 72
      #pragma unroll
      for (int i = 0; i < 4; ++i) {
        int p = i*256 + tid;
        int key = p >> 3, c8 = p & 7;
        bf16x8 kv = *(const bf16x8*)(kg + (size_t)(kb_ + key)*64 + c8*8);
        *(bf16x8*)(Ks + key*72 + c8*8) = kv;
      }
      // V^T chunk: bf16 [dim][key] stride 136 — pure copies
      #pragma unroll
      for (int i = 0; i < 4; ++i) {
        int p = i*256 + tid;
        int dim = p >> 4, k8 = p & 15;
        bf16x8 vv = *(const bf16x8*)(vtb + (size_t)dim*512 + c*128 + k8*8);
        *(bf16x8*)(Vt + dim*136 + k8*8) = vv;
      }
    }
    __syncthreads();

    for (int kc = 0; kc < 4; ++kc) {
      #pragma unroll
      for (int t = 0; t < 2; ++t) {
        const int kt = kc*2 + t;
        f32x4 s_acc;
        #pragma unroll
        for (int r = 0; r < 4; ++r) s_acc[r] = 0.f;
        const short* kp = Ks + (kt*16 + col)*72 + quad*8;
        bf16x8 kb0 = *(const bf16x8*)(kp);
        bf16x8 kb1 = *(const bf16x8*)(kp + 32);
        s_acc = __builtin_amdgcn_mfma_f32_16x16x32_bf16(qa[0], kb0, s_acc, 0,0,0);
        s_acc = __builtin_amdgcn_mfma_f32_16x16x32_bf16(qa[1], kb1, s_acc, 0,0,0);
        const int kcol = ((t*16 + col) ^ (quad*8));
        #pragma unroll
        for (int r = 0; r < 4; ++r) {
          uint32_t mw = Ms[wv][(quad*4+r)*16 + c*4 + (kt>>1)];
          float p = ((mw >> ((kt&1)*16 + col)) & 1u)
                      ? exp2f_(fminf(s_acc[r], 43.f)) : 0.f;   // s pre-scaled
          l_part[r] += p;
          Pl[wv][(quad*4+r)*32 + kcol] = (short)f2bf(p);
        }
      }
      bf16x8 pa = *(const bf16x8*)(&Pl[wv][col*32 + ((quad*8) ^ (((col)>>2)*8))]);
      #pragma unroll
      for (int nt = 0; nt < 4; ++nt) {
        bf16x8 vb = *(const bf16x8*)(&Vt[(nt*16+col)*136 + kc*32 + quad*8]);
        o_acc[nt] = __builtin_amdgcn_mfma_f32_16x16x32_bf16(pa, vb, o_acc[nt], 0,0,0);
      }
    }
  }

  float inv[4];
  #pragma unroll
  for (int r = 0; r < 4; ++r) {
    float v = l_part[r];
    v += __shfl_xor(v, 1);
    v += __shfl_xor(v, 2);
    v += __shfl_xor(v, 4);
    v += __shfl_xor(v, 8);
    inv[r] = 1.f / fmaxf(v, 1e-20f);
  }

  #pragma unroll
  for (int nt = 0; nt < 4; ++nt)
    #pragma unroll
    for (int r = 0; r < 4; ++r)
      feat[(size_t)(qbase + quad*4 + r)*128 + 64 + nt*16 + col] = o_acc[nt][r]*inv[r];
}

// ---------------------------------------------------------------------------
// forecast = feat @ Wf^T + bf
__global__ __launch_bounds__(256) void forecast_kernel(
    const float* __restrict__ feat, const float* __restrict__ Wf,
    const float* __restrict__ bf, float* __restrict__ out)
{
  __shared__ float4 Wl[768];
  __shared__ float  bl[24];
  const int tid = threadIdx.x;
  #pragma unroll
  for (int n = 0; n < 3; ++n) {
    int i = n*256 + tid;
    Wl[i] = ((const float4*)Wf)[i];
  }
  if (tid < 24) bl[tid] = bf[tid];
  __syncthreads();

  int g = blockIdx.x*256 + tid;
  if (g >= M_*24) return;
  int row = g / 24;
  int jj  = g - row*24;
  const float4* f4 = (const float4*)(feat + (size_t)row*128);
  float acc = bl[jj];
  #pragma unroll
  for (int kk = 0; kk < 32; ++kk) {
    int k4 = (kk + jj) & 31;
    acc += dot4(Wl[jj*32 + k4], f4[k4]);
  }
  out[g] = acc;
}

// ---------------------------------------------------------------------------
extern "C" void kernel_launch(void* const* d_in, const int* in_sizes, int n_in,
                              void* d_out, int out_size, void* d_ws, size_t ws_size,
                              hipStream_t stream)
{
  const float* obs = (const float*)d_in[0];
  const int*   pm  = (const int*)  d_in[1];
  const float* nhm = (const float*)d_in[2];
  const float* Wih = (const float*)d_in[3];
  const float* Whh = (const float*)d_in[4];
  const float* bih = (const float*)d_in[5];
  const float* bhh = (const float*)d_in[6];
  const float* W1  = (const float*)d_in[7];
  const float* b1  = (const float*)d_in[8];
  const float* W2  = (const float*)d_in[9];
  const float* b2  = (const float*)d_in[10];
  const float* Wh  = (const float*)d_in[11];
  const float* bh  = (const float*)d_in[12];
  const float* Wq  = (const float*)d_in[13];
  const float* bq  = (const float*)d_in[14];
  const float* Wk  = (const float*)d_in[15];
  const float* bk  = (const float*)d_in[16];
  const float* Wv  = (const float*)d_in[17];
  const float* bv  = (const float*)d_in[18];
  const float* Wf  = (const float*)d_in[19];
  const float* bf  = (const float*)d_in[20];

  float* out  = (float*)d_out;                 // forecast: 65536*24
  float* feat = out + (size_t)M_*24;           // feat:     65536*128

  // workspace: he(8MB) | qb(8MB) | kb(8MB) | vt(8MB) | bitmask(4.2MB)
  char* ws = (char*)d_ws;
  unsigned short* he  = (unsigned short*)(ws);
  unsigned short* qbf = (unsigned short*)(ws + (size_t) 8*1024*1024);
  unsigned short* kbf = (unsigned short*)(ws + (size_t)16*1024*1024);
  unsigned short* vtb = (unsigned short*)(ws + (size_t)24*1024*1024);
  uint32_t*       bmw = (uint32_t*)      (ws + (size_t)32*1024*1024);

  const int nmask = B_*N_*N_;
  maskpack_kernel<<<nmask/256, 256, 0, stream>>>(pm, bmw, nmask);
  lstm_kernel<<<M_/128, 512, 0, stream>>>(obs, nhm, Wih, Whh, bih, bhh, he);
  mlp_kernel<<<M_/64, 256, 0, stream>>>(he, W1,b1, W2,b2, Wh,bh, Wq,bq, Wk,bk, Wv,bv,
                                        qbf, kbf, vtb, feat);
  attn_kernel<<<M_/64, 256, 0, stream>>>(qbf, kbf, vtb, bmw, feat);
  forecast_kernel<<<(M_*24 + 255)/256, 256, 0, stream>>>(feat, Wf, bf, out);
}

// Round 6
// 439.679 us; speedup vs baseline: 2.1688x; 2.1688x over previous
//
#include <hip/hip_runtime.h>
#include <hip/hip_bf16.h>
#include <stdint.h>

#define B_ 128
#define N_ 512
#define S_ 8
#define H_ 64
#define M_ (B_*N_)          // 65536 rows
#define L2E 1.442695041f

typedef __attribute__((ext_vector_type(8))) short bf16x8;
typedef __attribute__((ext_vector_type(4))) float f32x4;

__device__ __forceinline__ float exp2f_(float x) { return __builtin_amdgcn_exp2f(x); }
__device__ __forceinline__ float rcpf_(float x)  { return __builtin_amdgcn_rcpf(x); }
// x pre-scaled by log2(e):  sig2(x) == sigmoid(x / L2E)   (v_exp + v_rcp only)
__device__ __forceinline__ float sig2(float x)  { return rcpf_(1.f + exp2f_(-x)); }
// x pre-scaled by 2*log2(e): tanh2(x) == tanh(x / (2*L2E))
__device__ __forceinline__ float tanh2(float x) { return 1.f - 2.f*rcpf_(exp2f_(x) + 1.f); }
__device__ __forceinline__ float dot4(float4 a, float4 b) {
  return a.x*b.x + a.y*b.y + a.z*b.z + a.w*b.w;
}
// fp32 -> bf16 round-to-nearest-even
__device__ __forceinline__ unsigned short f2bf(float x) {
  unsigned int u = __float_as_uint(x);
  u += 0x7fffu + ((u >> 16) & 1u);
  return (unsigned short)(u >> 16);
}

// ---------------------------------------------------------------------------
// pad_mask (B,N,N) -> bitmask, 1 bit per (q,key).
__global__ __launch_bounds__(256) void maskpack_kernel(
    const int* __restrict__ pm, uint32_t* __restrict__ bm, int n)
{
  int g = blockIdx.x * 256 + threadIdx.x;
  if (g >= n) return;
  unsigned long long ball = __ballot(pm[g] != 0);
  int lane = threadIdx.x & 63;
  if (lane == 0)       bm[g >> 5] = (uint32_t)ball;
  else if (lane == 32) bm[g >> 5] = (uint32_t)(ball >> 32);
}

// ---------------------------------------------------------------------------
// MFMA LSTM v4. 256 threads = 4 waves; 64 rows/block (16 rows/wave).
// NO min-wave launch bound (R5's (512,4) capped VGPRs at 128 -> 2GB of
// scratch spill traffic). Per step, per tile: 3 chained MFMAs:
//   acc = (a1@b1) + (a0@b0) + ([x0,x1,1]@[Wih;bias])   with C0 = zero VGPRs
// -> zero per-step acc-init VALU, no bias/wi VGPRs. h bf16 in LDS (stride 72),
// single barrier (waves own disjoint h rows). sig/tanh via v_rcp_f32 (rcpf),
// not IEEE division.
__global__ __launch_bounds__(256) void lstm_kernel(
    const float* __restrict__ obs, const float* __restrict__ nhm,
    const float* __restrict__ Wih, const float* __restrict__ Whh,
    const float* __restrict__ bih, const float* __restrict__ bhh,
    unsigned short* __restrict__ he)
{
  __shared__ short Wfrag[32*512];      // 32 KB  Whh B-frags (bf16, gate-scaled)
  __shared__ short Wx[16*512];         // 16 KB  [Wih;bias] B-frags (k=0,1,2)
  __shared__ short h_s[64*72];         // 9 KB   bf16, stride 72
  __shared__ float x_s[64][18];        // 4.6 KB
  __shared__ int   len_s[64];

  const int tid  = threadIdx.x;
  const int lane = tid & 63;
  const int wv   = tid >> 6;           // 0..3
  const int w16  = wv * 16;
  const int quad = lane >> 4;
  const int col  = lane & 15;
  const int row0 = blockIdx.x * 64;

  // ---- stage Whh as bf16 B-fragments (gate-scaled) ----
  #pragma unroll
  for (int i = 0; i < 8; ++i) {
    int p = i*256 + tid;               // 2048 (frag,lane) entries
    int f = p >> 6, l = p & 63;
    int t16 = f >> 1, s = f & 1;
    int lq = l >> 4, lc = l & 15;
    const float sc = (t16 >= 8 && t16 < 12) ? (2.f*L2E) : L2E;
    const float* src = Whh + (size_t)(t16*16 + lc)*64 + s*32 + lq*8;
    short* dst = Wfrag + f*512 + l*8;
    #pragma unroll
    for (int j = 0; j < 8; ++j) dst[j] = (short)f2bf(src[j] * sc);
  }
  // ---- stage [Wih; bias] B-fragments: B[0][n]=Wih[n][0], B[1][n]=Wih[n][1],
  //      B[2][n]=bih[n]+bhh[n], rest 0 (all gate-scaled) ----
  #pragma unroll
  for (int i = 0; i < 4; ++i) {
    int p = i*256 + tid;               // 1024 (tile,lane) entries
    int t16 = p >> 6, l = p & 63;
    int lq = l >> 4, lc = l & 15;
    int n = t16*16 + lc;
    const float sc = (t16 >= 8 && t16 < 12) ? (2.f*L2E) : L2E;
    bf16x8 v;
    #pragma unroll
    for (int j = 0; j < 8; ++j) v[j] = 0;
    if (lq == 0) {
      v[0] = (short)f2bf(Wih[2*n + 0] * sc);
      v[1] = (short)f2bf(Wih[2*n + 1] * sc);
      v[2] = (short)f2bf((bih[n] + bhh[n]) * sc);
    }
    *(bf16x8*)(Wx + t16*512 + l*8) = v;
  }

  // zero h_s (2304 dwords)
  #pragma unroll
  for (int i = 0; i < 9; ++i) ((uint32_t*)h_s)[i*256 + tid] = 0u;

  if (tid < 64) {
    int r = tid;
    float xv0[8], xv1[8];
    int lzi = -1;
    for (int t = 0; t < 8; ++t) {
      float m = nhm[(size_t)(row0+r)*8 + t];
      float a = obs[((size_t)(row0+r)*8 + t)*2 + 0] * m;
      float b = obs[((size_t)(row0+r)*8 + t)*2 + 1] * m;
      xv0[t] = a; xv1[t] = b;
      if (a == 0.f) lzi = t;
    }
    for (int t = 0; t < 8; ++t) {
      bool kill = (t < lzi);
      x_s[r][t*2+0] = kill ? 0.f : xv0[t];
      x_s[r][t*2+1] = kill ? 0.f : xv1[t];
    }
    int len = 7 - lzi; if (len < 1) len = 1;
    len_s[r] = len;
  }
  __syncthreads();     // the ONLY barrier

  int lenr[4];
  #pragma unroll
  for (int r = 0; r < 4; ++r) lenr[r] = len_s[w16 + quad*4 + r];

  float c_[16];
  #pragma unroll
  for (int i = 0; i < 16; ++i) c_[i] = 0.f;

  const f32x4 zero4 = {0.f, 0.f, 0.f, 0.f};
  const bool q0 = (quad == 0);

  for (int t = 0; t < 8; ++t) {
    // ---- build A-frag for the x/bias MFMA: [x0, x1, 1, 0...] on quad 0 ----
    float2 xx = *(const float2*)(&x_s[w16 + col][t*2]);
    union { bf16x8 v; uint32_t u[4]; } ax;
    ax.u[0] = q0 ? ((uint32_t)f2bf(xx.x) | ((uint32_t)f2bf(xx.y) << 16)) : 0u;
    ax.u[1] = q0 ? 0x00003f80u : 0u;    // bf16(1.0) at k==2
    ax.u[2] = 0u; ax.u[3] = 0u;

    // A-frags of h (bf16, no converts)
    bf16x8 a0 = *(const bf16x8*)(h_s + (w16 + col)*72 + quad*8);
    bf16x8 a1 = *(const bf16x8*)(h_s + (w16 + col)*72 + 32 + quad*8);

    f32x4 acc[16];
    #pragma unroll
    for (int t16 = 0; t16 < 16; ++t16) {
      bf16x8 wx = *(const bf16x8*)(Wx + t16*512 + lane*8);
      bf16x8 b0 = *(const bf16x8*)(Wfrag + (t16*2+0)*512 + lane*8);
      bf16x8 b1 = *(const bf16x8*)(Wfrag + (t16*2+1)*512 + lane*8);
      acc[t16] = __builtin_amdgcn_mfma_f32_16x16x32_bf16(ax.v, wx, zero4, 0, 0, 0);
      acc[t16] = __builtin_amdgcn_mfma_f32_16x16x32_bf16(a0, b0, acc[t16], 0, 0, 0);
      acc[t16] = __builtin_amdgcn_mfma_f32_16x16x32_bf16(a1, b1, acc[t16], 0, 0, 0);
    }

    #pragma unroll
    for (int tt = 0; tt < 4; ++tt) {
      #pragma unroll
      for (int r = 0; r < 4; ++r) {
        if (t < lenr[r]) {
          float gi = acc[tt   ][r];
          float gf = acc[tt+ 4][r];
          float gg = acc[tt+ 8][r];
          float go = acc[tt+12][r];
          float cn = sig2(gf)*c_[tt*4+r] + sig2(gi)*tanh2(gg);
          c_[tt*4+r] = cn;
          h_s[(w16 + quad*4 + r)*72 + tt*16 + col] =
              (short)f2bf(sig2(go)*tanh2(cn*(2.f*L2E)));
        }
      }
    }
    // no per-step barrier: each wave owns its 16 h rows
  }

  // he = relu(h) bf16, wave-local b128 stores
  #pragma unroll
  for (int s = 0; s < 2; ++s) {
    int chunk = s*64 + lane;          // 128 chunks of 8 shorts per wave
    int rl = chunk >> 3, c8 = chunk & 7;
    bf16x8 v = *(const bf16x8*)(h_s + (w16 + rl)*72 + c8*8);
    #pragma unroll
    for (int j = 0; j < 8; ++j) {
      short sv = v[j];
      v[j] = (sv & (short)0x8000) ? (short)0 : sv;   // relu (handles -0.0)
    }
    *(bf16x8*)(he + (size_t)(row0 + w16 + rl)*64 + c8*8) = v;
  }
}

// ---------------------------------------------------------------------------
// MFMA MLP: 3x relu(64x64) -> hidden -> q,k,v. 64 rows/block, 16 rows/wave.
// q,k bf16 row-major; v -> fp32 feat[:, :64] AND bf16 transposed vt[b][dim][key]
// (attn V^T staging becomes pure b128 copies). Wq/bq pre-scaled by log2(e).
__global__ __launch_bounds__(256) void mlp_kernel(
    const unsigned short* __restrict__ he,
    const float* __restrict__ W1, const float* __restrict__ b1,
    const float* __restrict__ W2, const float* __restrict__ b2,
    const float* __restrict__ Wh, const float* __restrict__ bh,
    const float* __restrict__ Wq, const float* __restrict__ bq,
    const float* __restrict__ Wk, const float* __restrict__ bk,
    const float* __restrict__ Wv, const float* __restrict__ bv,
    unsigned short* __restrict__ qb, unsigned short* __restrict__ kb,
    unsigned short* __restrict__ vt, float* __restrict__ feat)
{
  __shared__ short Wm[3][8*512];       // 24 KB B-frags
  __shared__ float bias_s[6*64];       // 1.5 KB
  __shared__ short Atile[4][16*76];    // 9.5 KB per-wave relayout tiles

  const int tid  = threadIdx.x;
  const int lane = tid & 63;
  const int wv   = tid >> 6;
  const int quad = lane >> 4;
  const int col  = lane & 15;
  const int rowb = blockIdx.x*64 + wv*16;

  const float* m1[3] = {W1, W2, Wh};
  const float* m2[3] = {Wq, Wk, Wv};
  auto stage3 = [&](const float* const* mats, float sc0) {
    #pragma unroll
    for (int i = 0; i < 6; ++i) {
      int p = i*256 + tid;
      int m = p >> 9, rem = p & 511;
      int f = rem >> 6, l = rem & 63;
      int nt = f >> 1, s = f & 1;
      int lq = l >> 4, lc = l & 15;
      float sc = (m == 0) ? sc0 : 1.f;
      const float* src = mats[m] + (size_t)(nt*16 + lc)*64 + s*32 + lq*8;
      short* dst = &Wm[m][f*512 + l*8];
      #pragma unroll
      for (int j = 0; j < 8; ++j) dst[j] = (short)f2bf(src[j] * sc);
    }
  };
  stage3(m1, 1.f);
  {
    const float* bs[6] = {b1, b2, bh, bq, bk, bv};
    for (int i = tid; i < 384; i += 256) {
      float sc = ((i >> 6) == 3) ? L2E : 1.f;      // bq scaled by log2(e)
      bias_s[i] = bs[i>>6][i & 63] * sc;
    }
  }
  __syncthreads();

  bf16x8 a0 = *(const bf16x8*)(he + (size_t)(rowb + col)*64 + quad*8);
  bf16x8 a1 = *(const bf16x8*)(he + (size_t)(rowb + col)*64 + quad*8 + 32);

  f32x4 acc[4];
  auto runL = [&](int m, int bidx) {
    #pragma unroll
    for (int nt = 0; nt < 4; ++nt) {
      float bb = bias_s[bidx*64 + nt*16 + col];
      acc[nt][0] = bb; acc[nt][1] = bb; acc[nt][2] = bb; acc[nt][3] = bb;
    }
    #pragma unroll
    for (int nt = 0; nt < 4; ++nt) {
      bf16x8 bf0 = *(const bf16x8*)(&Wm[m][(nt*2+0)*512 + lane*8]);
      bf16x8 bf1 = *(const bf16x8*)(&Wm[m][(nt*2+1)*512 + lane*8]);
      acc[nt] = __builtin_amdgcn_mfma_f32_16x16x32_bf16(a0, bf0, acc[nt], 0,0,0);
      acc[nt] = __builtin_amdgcn_mfma_f32_16x16x32_bf16(a1, bf1, acc[nt], 0,0,0);
    }
  };
  auto tileWrite = [&](bool relu) {
    #pragma unroll
    for (int nt = 0; nt < 4; ++nt)
      #pragma unroll
      for (int r = 0; r < 4; ++r) {
        float v = relu ? fmaxf(acc[nt][r], 0.f) : acc[nt][r];
        Atile[wv][(quad*4+r)*76 + ((nt*16+col) ^ (r*16))] = (short)f2bf(v);
      }
  };
  auto tileReadA = [&]() {
    int sw = (col & 3) * 16;
    a0 = *(const bf16x8*)(&Atile[wv][col*76 + ((quad*8     ) ^ sw)]);
    a1 = *(const bf16x8*)(&Atile[wv][col*76 + ((quad*8 + 32) ^ sw)]);
  };
  auto storeBF = [&](unsigned short* dst) {
    #pragma unroll
    for (int s = 0; s < 2; ++s) {
      int chunk = s*64 + lane;
      int r = chunk >> 3, c8 = chunk & 7;
      bf16x8 v = *(const bf16x8*)(&Atile[wv][r*76 + ((c8*8) ^ ((r&3)*16))]);
      *(bf16x8*)(dst + (size_t)(rowb + r)*64 + c8*8) = v;
    }
  };

  runL(0, 0); tileWrite(true); tileReadA();
  runL(1, 1); tileWrite(true); tileReadA();
  runL(2, 2); tileWrite(true); tileReadA();      // a0/a1 = hidden A-frags
  __syncthreads();
  stage3(m2, L2E);                               // Wq scaled by log2(e)
  __syncthreads();

  runL(0, 3); tileWrite(false); storeBF(qb);     // q (bf16, L2E-scaled)
  runL(1, 4); tileWrite(false); storeBF(kb);     // k (bf16)
  runL(2, 5);                                    // v
  {
    const int bi   = rowb >> 9;                  // batch
    const int key0 = (rowb & 511) + quad*4;
    #pragma unroll
    for (int nt = 0; nt < 4; ++nt) {
      #pragma unroll
      for (int r = 0; r < 4; ++r)
        feat[(size_t)(rowb + quad*4 + r)*128 + nt*16 + col] = acc[nt][r];
      uint32_t lo = (uint32_t)f2bf(acc[nt][0]) | ((uint32_t)f2bf(acc[nt][1]) << 16);
      uint32_t hi = (uint32_t)f2bf(acc[nt][2]) | ((uint32_t)f2bf(acc[nt][3]) << 16);
      uint2 pk; pk.x = lo; pk.y = hi;
      *(uint2*)(vt + ((size_t)bi*64 + nt*16 + col)*512 + key0) = pk;
    }
  }
}

// ---------------------------------------------------------------------------
// MFMA attention. q pre-scaled by log2(e); V^T staging = pure b128 copies.
__global__ __launch_bounds__(256) void attn_kernel(
    const unsigned short* __restrict__ qg, const unsigned short* __restrict__ kg,
    const unsigned short* __restrict__ vt,
    const uint32_t* __restrict__ bm, float* __restrict__ feat)
{
  __shared__ short    Ks[128*72];      // 18.0 KB
  __shared__ short    Vt[64*136];      // 17.0 KB
  __shared__ short    Pl[4][16*32];    // 4 KB, per-wave
  __shared__ uint32_t Ms[4][256];      // 4 KB, per-wave mask words

  const int tid  = threadIdx.x;
  const int lane = tid & 63;
  const int wv   = tid >> 6;
  const int quad = lane >> 4;
  const int col  = lane & 15;

  const int b     = blockIdx.x >> 3;
  const int q0    = (blockIdx.x & 7) * 64;
  const int qbase = b*512 + q0 + wv*16;

  bf16x8 qa[2];
  qa[0] = *(const bf16x8*)(qg + (size_t)(qbase + col)*64 + quad*8);
  qa[1] = *(const bf16x8*)(qg + (size_t)(qbase + col)*64 + quad*8 + 32);

  #pragma unroll
  for (int w = 0; w < 4; ++w)
    Ms[wv][w*64 + lane] = bm[(size_t)qbase*16 + w*64 + lane];

  f32x4 o_acc[4];
  #pragma unroll
  for (int nt = 0; nt < 4; ++nt)
    #pragma unroll
    for (int r = 0; r < 4; ++r) o_acc[nt][r] = 0.f;
  float l_part[4] = {0.f, 0.f, 0.f, 0.f};

  const unsigned short* vtb = vt + (size_t)b*64*512;

  for (int c = 0; c < 4; ++c) {
    __syncthreads();
    {
      const int kb_ = b*512 + c*128;
      // K chunk: bf16 [key][dim] stride 72
      #pragma unroll
      for (int i = 0; i < 4; ++i) {
        int p = i*256 + tid;
        int key = p >> 3, c8 = p & 7;
        bf16x8 kv = *(const bf16x8*)(kg + (size_t)(kb_ + key)*64 + c8*8);
        *(bf16x8*)(Ks + key*72 + c8*8) = kv;
      }
      // V^T chunk: bf16 [dim][key] stride 136 — pure copies
      #pragma unroll
      for (int i = 0; i < 4; ++i) {
        int p = i*256 + tid;
        int dim = p >> 4, k8 = p & 15;
        bf16x8 vv = *(const bf16x8*)(vtb + (size_t)dim*512 + c*128 + k8*8);
        *(bf16x8*)(Vt + dim*136 + k8*8) = vv;
      }
    }
    __syncthreads();

    for (int kc = 0; kc < 4; ++kc) {
      #pragma unroll
      for (int t = 0; t < 2; ++t) {
        const int kt = kc*2 + t;
        f32x4 s_acc;
        #pragma unroll
        for (int r = 0; r < 4; ++r) s_acc[r] = 0.f;
        const short* kp = Ks + (kt*16 + col)*72 + quad*8;
        bf16x8 kb0 = *(const bf16x8*)(kp);
        bf16x8 kb1 = *(const bf16x8*)(kp + 32);
        s_acc = __builtin_amdgcn_mfma_f32_16x16x32_bf16(qa[0], kb0, s_acc, 0,0,0);
        s_acc = __builtin_amdgcn_mfma_f32_16x16x32_bf16(qa[1], kb1, s_acc, 0,0,0);
        const int kcol = ((t*16 + col) ^ (quad*8));
        #pragma unroll
        for (int r = 0; r < 4; ++r) {
          uint32_t mw = Ms[wv][(quad*4+r)*16 + c*4 + (kt>>1)];
          float p = ((mw >> ((kt&1)*16 + col)) & 1u)
                      ? exp2f_(fminf(s_acc[r], 43.f)) : 0.f;   // s pre-scaled
          l_part[r] += p;
          Pl[wv][(quad*4+r)*32 + kcol] = (short)f2bf(p);
        }
      }
      bf16x8 pa = *(const bf16x8*)(&Pl[wv][col*32 + ((quad*8) ^ (((col)>>2)*8))]);
      #pragma unroll
      for (int nt = 0; nt < 4; ++nt) {
        bf16x8 vb = *(const bf16x8*)(&Vt[(nt*16+col)*136 + kc*32 + quad*8]);
        o_acc[nt] = __builtin_amdgcn_mfma_f32_16x16x32_bf16(pa, vb, o_acc[nt], 0,0,0);
      }
    }
  }

  float inv[4];
  #pragma unroll
  for (int r = 0; r < 4; ++r) {
    float v = l_part[r];
    v += __shfl_xor(v, 1);
    v += __shfl_xor(v, 2);
    v += __shfl_xor(v, 4);
    v += __shfl_xor(v, 8);
    inv[r] = rcpf_(fmaxf(v, 1e-20f));
  }

  #pragma unroll
  for (int nt = 0; nt < 4; ++nt)
    #pragma unroll
    for (int r = 0; r < 4; ++r)
      feat[(size_t)(qbase + quad*4 + r)*128 + 64 + nt*16 + col] = o_acc[nt][r]*inv[r];
}

// ---------------------------------------------------------------------------
// forecast = feat @ Wf^T + bf
__global__ __launch_bounds__(256) void forecast_kernel(
    const float* __restrict__ feat, const float* __restrict__ Wf,
    const float* __restrict__ bf, float* __restrict__ out)
{
  __shared__ float4 Wl[768];
  __shared__ float  bl[24];
  const int tid = threadIdx.x;
  #pragma unroll
  for (int n = 0; n < 3; ++n) {
    int i = n*256 + tid;
    Wl[i] = ((const float4*)Wf)[i];
  }
  if (tid < 24) bl[tid] = bf[tid];
  __syncthreads();

  int g = blockIdx.x*256 + tid;
  if (g >= M_*24) return;
  int row = g / 24;
  int jj  = g - row*24;
  const float4* f4 = (const float4*)(feat + (size_t)row*128);
  float acc = bl[jj];
  #pragma unroll
  for (int kk = 0; kk < 32; ++kk) {
    int k4 = (kk + jj) & 31;
    acc += dot4(Wl[jj*32 + k4], f4[k4]);
  }
  out[g] = acc;
}

// ---------------------------------------------------------------------------
extern "C" void kernel_launch(void* const* d_in, const int* in_sizes, int n_in,
                              void* d_out, int out_size, void* d_ws, size_t ws_size,
                              hipStream_t stream)
{
  const float* obs = (const float*)d_in[0];
  const int*   pm  = (const int*)  d_in[1];
  const float* nhm = (const float*)d_in[2];
  const float* Wih = (const float*)d_in[3];
  const float* Whh = (const float*)d_in[4];
  const float* bih = (const float*)d_in[5];
  const float* bhh = (const float*)d_in[6];
  const float* W1  = (const float*)d_in[7];
  const float* b1  = (const float*)d_in[8];
  const float* W2  = (const float*)d_in[9];
  const float* b2  = (const float*)d_in[10];
  const float* Wh  = (const float*)d_in[11];
  const float* bh  = (const float*)d_in[12];
  const float* Wq  = (const float*)d_in[13];
  const float* bq  = (const float*)d_in[14];
  const float* Wk  = (const float*)d_in[15];
  const float* bk  = (const float*)d_in[16];
  const float* Wv  = (const float*)d_in[17];
  const float* bv  = (const float*)d_in[18];
  const float* Wf  = (const float*)d_in[19];
  const float* bf  = (const float*)d_in[20];

  float* out  = (float*)d_out;                 // forecast: 65536*24
  float* feat = out + (size_t)M_*24;           // feat:     65536*128

  // workspace: he(8MB) | qb(8MB) | kb(8MB) | vt(8MB) | bitmask(4.2MB)
  char* ws = (char*)d_ws;
  unsigned short* he  = (unsigned short*)(ws);
  unsigned short* qbf = (unsigned short*)(ws + (size_t) 8*1024*1024);
  unsigned short* kbf = (unsigned short*)(ws + (size_t)16*1024*1024);
  unsigned short* vtb = (unsigned short*)(ws + (size_t)24*1024*1024);
  uint32_t*       bmw = (uint32_t*)      (ws + (size_t)32*1024*1024);

  const int nmask = B_*N_*N_;
  maskpack_kernel<<<nmask/256, 256, 0, stream>>>(pm, bmw, nmask);
  lstm_kernel<<<M_/64, 256, 0, stream>>>(obs, nhm, Wih, Whh, bih, bhh, he);
  mlp_kernel<<<M_/64, 256, 0, stream>>>(he, W1,b1, W2,b2, Wh,bh, Wq,bq, Wk,bk, Wv,bv,
                                        qbf, kbf, vtb, feat);
  attn_kernel<<<M_/64, 256, 0, stream>>>(qbf, kbf, vtb, bmw, feat);
  forecast_kernel<<<(M_*24 + 255)/256, 256, 0, stream>>>(feat, Wf, bf, out);
}

// Round 8
// 408.283 us; speedup vs baseline: 2.3356x; 1.0769x over previous
//
#include <hip/hip_runtime.h>
#include <hip/hip_bf16.h>
#include <stdint.h>

#define B_ 128
#define N_ 512
#define S_ 8
#define H_ 64
#define M_ (B_*N_)          // 65536 rows
#define L2E 1.442695041f

typedef __attribute__((ext_vector_type(8))) short bf16x8;
typedef __attribute__((ext_vector_type(4))) float f32x4;

__device__ __forceinline__ float exp2f_(float x) { return __builtin_amdgcn_exp2f(x); }
__device__ __forceinline__ float rcpf_(float x)  { return __builtin_amdgcn_rcpf(x); }
// x pre-scaled by log2(e):  sig2(x) == sigmoid(x / L2E)   (v_exp + v_rcp only)
__device__ __forceinline__ float sig2(float x)  { return rcpf_(1.f + exp2f_(-x)); }
// x pre-scaled by 2*log2(e): tanh2(x) == tanh(x / (2*L2E))
__device__ __forceinline__ float tanh2(float x) { return 1.f - 2.f*rcpf_(exp2f_(x) + 1.f); }
__device__ __forceinline__ float dot4(float4 a, float4 b) {
  return a.x*b.x + a.y*b.y + a.z*b.z + a.w*b.w;
}
// fp32 -> bf16 round-to-nearest-even
__device__ __forceinline__ unsigned short f2bf(float x) {
  unsigned int u = __float_as_uint(x);
  u += 0x7fffu + ((u >> 16) & 1u);
  return (unsigned short)(u >> 16);
}

// ---------------------------------------------------------------------------
// pad_mask (B,N,N) -> bitmask, 1 bit per (q,key).
__global__ __launch_bounds__(256) void maskpack_kernel(
    const int* __restrict__ pm, uint32_t* __restrict__ bm, int n)
{
  int g = blockIdx.x * 256 + threadIdx.x;
  if (g >= n) return;
  unsigned long long ball = __ballot(pm[g] != 0);
  int lane = threadIdx.x & 63;
  if (lane == 0)       bm[g >> 5] = (uint32_t)ball;
  else if (lane == 32) bm[g >> 5] = (uint32_t)(ball >> 32);
}

// ---------------------------------------------------------------------------
// MFMA LSTM v5b. 256 threads = 4 waves; 64 rows/block (16 rows/wave).
// Compact Wx (2KB). FIX vs v5: ALL lanes read an initialized Wxc entry
// (t16*64 + col*4); non-quad0 lanes zero the fragment by v_cndmask on the
// VALUE (v5's conditional *address* hit uninitialized LDS for t16>=1).
// LDS ~49KB -> 3 blocks/CU. 3 chained MFMAs/tile, C0 = zero VGPRs.
// h bf16 in LDS; single barrier; rcp-based sig/tanh.
__global__ __launch_bounds__(256) void lstm_kernel(
    const float* __restrict__ obs, const float* __restrict__ nhm,
    const float* __restrict__ Wih, const float* __restrict__ Whh,
    const float* __restrict__ bih, const float* __restrict__ bhh,
    unsigned short* __restrict__ he)
{
  __shared__ short Wfrag[32*512];      // 32 KB  Whh B-frags (bf16, gate-scaled)
  __shared__ short Wxc[1024];          // 2 KB   compact [Wih0,Wih1,bias,0] per n
  __shared__ short h_s[64*72];         // 9 KB   bf16, stride 72
  __shared__ float x_s[64][18];        // 4.6 KB
  __shared__ int   len_s[64];

  const int tid  = threadIdx.x;
  const int lane = tid & 63;
  const int wv   = tid >> 6;           // 0..3
  const int w16  = wv * 16;
  const int quad = lane >> 4;
  const int col  = lane & 15;
  const int row0 = blockIdx.x * 64;

  // ---- stage Whh as bf16 B-fragments (gate-scaled) ----
  #pragma unroll
  for (int i = 0; i < 8; ++i) {
    int p = i*256 + tid;               // 2048 (frag,lane) entries
    int f = p >> 6, l = p & 63;
    int t16 = f >> 1, s = f & 1;
    int lq = l >> 4, lc = l & 15;
    const float sc = (t16 >= 8 && t16 < 12) ? (2.f*L2E) : L2E;
    const float* src = Whh + (size_t)(t16*16 + lc)*64 + s*32 + lq*8;
    short* dst = Wfrag + f*512 + l*8;
    #pragma unroll
    for (int j = 0; j < 8; ++j) dst[j] = (short)f2bf(src[j] * sc);
  }
  // ---- stage compact Wx: Wxc[t16*64 + cc*4 + k], k: 0=Wih0 1=Wih1 2=bias ----
  {
    int t16 = tid >> 4, cc = tid & 15;
    int n = t16*16 + cc;
    const float sc = (t16 >= 8 && t16 < 12) ? (2.f*L2E) : L2E;
    short* d = Wxc + t16*64 + cc*4;
    d[0] = (short)f2bf(Wih[2*n + 0] * sc);
    d[1] = (short)f2bf(Wih[2*n + 1] * sc);
    d[2] = (short)f2bf((bih[n] + bhh[n]) * sc);
    d[3] = 0;
  }

  // zero h_s (2304 dwords)
  #pragma unroll
  for (int i = 0; i < 9; ++i) ((uint32_t*)h_s)[i*256 + tid] = 0u;

  if (tid < 64) {
    int r = tid;
    float xv0[8], xv1[8];
    int lzi = -1;
    for (int t = 0; t < 8; ++t) {
      float m = nhm[(size_t)(row0+r)*8 + t];
      float a = obs[((size_t)(row0+r)*8 + t)*2 + 0] * m;
      float b = obs[((size_t)(row0+r)*8 + t)*2 + 1] * m;
      xv0[t] = a; xv1[t] = b;
      if (a == 0.f) lzi = t;
    }
    for (int t = 0; t < 8; ++t) {
      bool kill = (t < lzi);
      x_s[r][t*2+0] = kill ? 0.f : xv0[t];
      x_s[r][t*2+1] = kill ? 0.f : xv1[t];
    }
    int len = 7 - lzi; if (len < 1) len = 1;
    len_s[r] = len;
  }
  __syncthreads();     // the ONLY barrier

  int lenr[4];
  #pragma unroll
  for (int r = 0; r < 4; ++r) lenr[r] = len_s[w16 + quad*4 + r];

  float c_[16];
  #pragma unroll
  for (int i = 0; i < 16; ++i) c_[i] = 0.f;

  const f32x4 zero4 = {0.f, 0.f, 0.f, 0.f};
  const bool q0 = (quad == 0);

  for (int t = 0; t < 8; ++t) {
    // ---- A-frag for the x/bias MFMA: [x0, x1, 1, 0...] on quad 0 ----
    float2 xx = *(const float2*)(&x_s[w16 + col][t*2]);
    union { bf16x8 v; uint32_t u[4]; } ax;
    ax.u[0] = q0 ? ((uint32_t)f2bf(xx.x) | ((uint32_t)f2bf(xx.y) << 16)) : 0u;
    ax.u[1] = q0 ? 0x00003f80u : 0u;    // bf16(1.0) at k==2
    ax.u[2] = 0u; ax.u[3] = 0u;

    // A-frags of h (bf16, no converts)
    bf16x8 a0 = *(const bf16x8*)(h_s + (w16 + col)*72 + quad*8);
    bf16x8 a1 = *(const bf16x8*)(h_s + (w16 + col)*72 + 32 + quad*8);

    f32x4 acc[16];
    #pragma unroll
    for (int t16 = 0; t16 < 16; ++t16) {
      union { bf16x8 v; uint32_t u[4]; } wx;
      uint2 d = *(const uint2*)(Wxc + t16*64 + col*4);  // always initialized
      wx.u[0] = q0 ? d.x : 0u;          // zero fragment on non-quad0 lanes
      wx.u[1] = q0 ? d.y : 0u;
      wx.u[2] = 0u; wx.u[3] = 0u;
      bf16x8 b0 = *(const bf16x8*)(Wfrag + (t16*2+0)*512 + lane*8);
      bf16x8 b1 = *(const bf16x8*)(Wfrag + (t16*2+1)*512 + lane*8);
      acc[t16] = __builtin_amdgcn_mfma_f32_16x16x32_bf16(ax.v, wx.v, zero4, 0, 0, 0);
      acc[t16] = __builtin_amdgcn_mfma_f32_16x16x32_bf16(a0, b0, acc[t16], 0, 0, 0);
      acc[t16] = __builtin_amdgcn_mfma_f32_16x16x32_bf16(a1, b1, acc[t16], 0, 0, 0);
    }

    #pragma unroll
    for (int tt = 0; tt < 4; ++tt) {
      #pragma unroll
      for (int r = 0; r < 4; ++r) {
        if (t < lenr[r]) {
          float gi = acc[tt   ][r];
          float gf = acc[tt+ 4][r];
          float gg = acc[tt+ 8][r];
          float go = acc[tt+12][r];
          float cn = sig2(gf)*c_[tt*4+r] + sig2(gi)*tanh2(gg);
          c_[tt*4+r] = cn;
          h_s[(w16 + quad*4 + r)*72 + tt*16 + col] =
              (short)f2bf(sig2(go)*tanh2(cn*(2.f*L2E)));
        }
      }
    }
    // no per-step barrier: each wave owns its 16 h rows
  }

  // he = relu(h) bf16, wave-local b128 stores
  #pragma unroll
  for (int s = 0; s < 2; ++s) {
    int chunk = s*64 + lane;          // 128 chunks of 8 shorts per wave
    int rl = chunk >> 3, c8 = chunk & 7;
    bf16x8 v = *(const bf16x8*)(h_s + (w16 + rl)*72 + c8*8);
    #pragma unroll
    for (int j = 0; j < 8; ++j) {
      short sv = v[j];
      v[j] = (sv & (short)0x8000) ? (short)0 : sv;   // relu (handles -0.0)
    }
    *(bf16x8*)(he + (size_t)(row0 + w16 + rl)*64 + c8*8) = v;
  }
}

// ---------------------------------------------------------------------------
// MFMA MLP (unchanged)
__global__ __launch_bounds__(256) void mlp_kernel(
    const unsigned short* __restrict__ he,
    const float* __restrict__ W1, const float* __restrict__ b1,
    const float* __restrict__ W2, const float* __restrict__ b2,
    const float* __restrict__ Wh, const float* __restrict__ bh,
    const float* __restrict__ Wq, const float* __restrict__ bq,
    const float* __restrict__ Wk, const float* __restrict__ bk,
    const float* __restrict__ Wv, const float* __restrict__ bv,
    unsigned short* __restrict__ qb, unsigned short* __restrict__ kb,
    unsigned short* __restrict__ vt, float* __restrict__ feat)
{
  __shared__ short Wm[3][8*512];       // 24 KB B-frags
  __shared__ float bias_s[6*64];       // 1.5 KB
  __shared__ short Atile[4][16*76];    // 9.5 KB per-wave relayout tiles

  const int tid  = threadIdx.x;
  const int lane = tid & 63;
  const int wv   = tid >> 6;
  const int quad = lane >> 4;
  const int col  = lane & 15;
  const int rowb = blockIdx.x*64 + wv*16;

  const float* m1[3] = {W1, W2, Wh};
  const float* m2[3] = {Wq, Wk, Wv};
  auto stage3 = [&](const float* const* mats, float sc0) {
    #pragma unroll
    for (int i = 0; i < 6; ++i) {
      int p = i*256 + tid;
      int m = p >> 9, rem = p & 511;
      int f = rem >> 6, l = rem & 63;
      int nt = f >> 1, s = f & 1;
      int lq = l >> 4, lc = l & 15;
      float sc = (m == 0) ? sc0 : 1.f;
      const float* src = mats[m] + (size_t)(nt*16 + lc)*64 + s*32 + lq*8;
      short* dst = &Wm[m][f*512 + l*8];
      #pragma unroll
      for (int j = 0; j < 8; ++j) dst[j] = (short)f2bf(src[j] * sc);
    }
  };
  stage3(m1, 1.f);
  {
    const float* bs[6] = {b1, b2, bh, bq, bk, bv};
    for (int i = tid; i < 384; i += 256) {
      float sc = ((i >> 6) == 3) ? L2E : 1.f;      // bq scaled by log2(e)
      bias_s[i] = bs[i>>6][i & 63] * sc;
    }
  }
  __syncthreads();

  bf16x8 a0 = *(const bf16x8*)(he + (size_t)(rowb + col)*64 + quad*8);
  bf16x8 a1 = *(const bf16x8*)(he + (size_t)(rowb + col)*64 + quad*8 + 32);

  f32x4 acc[4];
  auto runL = [&](int m, int bidx) {
    #pragma unroll
    for (int nt = 0; nt < 4; ++nt) {
      float bb = bias_s[bidx*64 + nt*16 + col];
      acc[nt][0] = bb; acc[nt][1] = bb; acc[nt][2] = bb; acc[nt][3] = bb;
    }
    #pragma unroll
    for (int nt = 0; nt < 4; ++nt) {
      bf16x8 bf0 = *(const bf16x8*)(&Wm[m][(nt*2+0)*512 + lane*8]);
      bf16x8 bf1 = *(const bf16x8*)(&Wm[m][(nt*2+1)*512 + lane*8]);
      acc[nt] = __builtin_amdgcn_mfma_f32_16x16x32_bf16(a0, bf0, acc[nt], 0,0,0);
      acc[nt] = __builtin_amdgcn_mfma_f32_16x16x32_bf16(a1, bf1, acc[nt], 0,0,0);
    }
  };
  auto tileWrite = [&](bool relu) {
    #pragma unroll
    for (int nt = 0; nt < 4; ++nt)
      #pragma unroll
      for (int r = 0; r < 4; ++r) {
        float v = relu ? fmaxf(acc[nt][r], 0.f) : acc[nt][r];
        Atile[wv][(quad*4+r)*76 + ((nt*16+col) ^ (r*16))] = (short)f2bf(v);
      }
  };
  auto tileReadA = [&]() {
    int sw = (col & 3) * 16;
    a0 = *(const bf16x8*)(&Atile[wv][col*76 + ((quad*8     ) ^ sw)]);
    a1 = *(const bf16x8*)(&Atile[wv][col*76 + ((quad*8 + 32) ^ sw)]);
  };
  auto storeBF = [&](unsigned short* dst) {
    #pragma unroll
    for (int s = 0; s < 2; ++s) {
      int chunk = s*64 + lane;
      int r = chunk >> 3, c8 = chunk & 7;
      bf16x8 v = *(const bf16x8*)(&Atile[wv][r*76 + ((c8*8) ^ ((r&3)*16))]);
      *(bf16x8*)(dst + (size_t)(rowb + r)*64 + c8*8) = v;
    }
  };

  runL(0, 0); tileWrite(true); tileReadA();
  runL(1, 1); tileWrite(true); tileReadA();
  runL(2, 2); tileWrite(true); tileReadA();      // a0/a1 = hidden A-frags
  __syncthreads();
  stage3(m2, L2E);                               // Wq scaled by log2(e)
  __syncthreads();

  runL(0, 3); tileWrite(false); storeBF(qb);     // q (bf16, L2E-scaled)
  runL(1, 4); tileWrite(false); storeBF(kb);     // k (bf16)
  runL(2, 5);                                    // v
  {
    const int bi   = rowb >> 9;                  // batch
    const int key0 = (rowb & 511) + quad*4;
    #pragma unroll
    for (int nt = 0; nt < 4; ++nt) {
      #pragma unroll
      for (int r = 0; r < 4; ++r)
        feat[(size_t)(rowb + quad*4 + r)*128 + nt*16 + col] = acc[nt][r];
      uint32_t lo = (uint32_t)f2bf(acc[nt][0]) | ((uint32_t)f2bf(acc[nt][1]) << 16);
      uint32_t hi = (uint32_t)f2bf(acc[nt][2]) | ((uint32_t)f2bf(acc[nt][3]) << 16);
      uint2 pk; pk.x = lo; pk.y = hi;
      *(uint2*)(vt + ((size_t)bi*64 + nt*16 + col)*512 + key0) = pk;
    }
  }
}

// ---------------------------------------------------------------------------
// MFMA attention (unchanged)
__global__ __launch_bounds__(256) void attn_kernel(
    const unsigned short* __restrict__ qg, const unsigned short* __restrict__ kg,
    const unsigned short* __restrict__ vt,
    const uint32_t* __restrict__ bm, float* __restrict__ feat)
{
  __shared__ short    Ks[128*72];      // 18.0 KB
  __shared__ short    Vt[64*136];      // 17.0 KB
  __shared__ short    Pl[4][16*32];    // 4 KB, per-wave
  __shared__ uint32_t Ms[4][256];      // 4 KB, per-wave mask words

  const int tid  = threadIdx.x;
  const int lane = tid & 63;
  const int wv   = tid >> 6;
  const int quad = lane >> 4;
  const int col  = lane & 15;

  const int b     = blockIdx.x >> 3;
  const int q0    = (blockIdx.x & 7) * 64;
  const int qbase = b*512 + q0 + wv*16;

  bf16x8 qa[2];
  qa[0] = *(const bf16x8*)(qg + (size_t)(qbase + col)*64 + quad*8);
  qa[1] = *(const bf16x8*)(qg + (size_t)(qbase + col)*64 + quad*8 + 32);

  #pragma unroll
  for (int w = 0; w < 4; ++w)
    Ms[wv][w*64 + lane] = bm[(size_t)qbase*16 + w*64 + lane];

  f32x4 o_acc[4];
  #pragma unroll
  for (int nt = 0; nt < 4; ++nt)
    #pragma unroll
    for (int r = 0; r < 4; ++r) o_acc[nt][r] = 0.f;
  float l_part[4] = {0.f, 0.f, 0.f, 0.f};

  const unsigned short* vtb = vt + (size_t)b*64*512;

  for (int c = 0; c < 4; ++c) {
    __syncthreads();
    {
      const int kb_ = b*512 + c*128;
      // K chunk: bf16 [key][dim] stride 72
      #pragma unroll
      for (int i = 0; i < 4; ++i) {
        int p = i*256 + tid;
        int key = p >> 3, c8 = p & 7;
        bf16x8 kv = *(const bf16x8*)(kg + (size_t)(kb_ + key)*64 + c8*8);
        *(bf16x8*)(Ks + key*72 + c8*8) = kv;
      }
      // V^T chunk: bf16 [dim][key] stride 136 — pure copies
      #pragma unroll
      for (int i = 0; i < 4; ++i) {
        int p = i*256 + tid;
        int dim = p >> 4, k8 = p & 15;
        bf16x8 vv = *(const bf16x8*)(vtb + (size_t)dim*512 + c*128 + k8*8);
        *(bf16x8*)(Vt + dim*136 + k8*8) = vv;
      }
    }
    __syncthreads();

    for (int kc = 0; kc < 4; ++kc) {
      #pragma unroll
      for (int t = 0; t < 2; ++t) {
        const int kt = kc*2 + t;
        f32x4 s_acc;
        #pragma unroll
        for (int r = 0; r < 4; ++r) s_acc[r] = 0.f;
        const short* kp = Ks + (kt*16 + col)*72 + quad*8;
        bf16x8 kb0 = *(const bf16x8*)(kp);
        bf16x8 kb1 = *(const bf16x8*)(kp + 32);
        s_acc = __builtin_amdgcn_mfma_f32_16x16x32_bf16(qa[0], kb0, s_acc, 0,0,0);
        s_acc = __builtin_amdgcn_mfma_f32_16x16x32_bf16(qa[1], kb1, s_acc, 0,0,0);
        const int kcol = ((t*16 + col) ^ (quad*8));
        #pragma unroll
        for (int r = 0; r < 4; ++r) {
          uint32_t mw = Ms[wv][(quad*4+r)*16 + c*4 + (kt>>1)];
          float p = ((mw >> ((kt&1)*16 + col)) & 1u)
                      ? exp2f_(fminf(s_acc[r], 43.f)) : 0.f;   // s pre-scaled
          l_part[r] += p;
          Pl[wv][(quad*4+r)*32 + kcol] = (short)f2bf(p);
        }
      }
      bf16x8 pa = *(const bf16x8*)(&Pl[wv][col*32 + ((quad*8) ^ (((col)>>2)*8))]);
      #pragma unroll
      for (int nt = 0; nt < 4; ++nt) {
        bf16x8 vb = *(const bf16x8*)(&Vt[(nt*16+col)*136 + kc*32 + quad*8]);
        o_acc[nt] = __builtin_amdgcn_mfma_f32_16x16x32_bf16(pa, vb, o_acc[nt], 0,0,0);
      }
    }
  }

  float inv[4];
  #pragma unroll
  for (int r = 0; r < 4; ++r) {
    float v = l_part[r];
    v += __shfl_xor(v, 1);
    v += __shfl_xor(v, 2);
    v += __shfl_xor(v, 4);
    v += __shfl_xor(v, 8);
    inv[r] = rcpf_(fmaxf(v, 1e-20f));
  }

  #pragma unroll
  for (int nt = 0; nt < 4; ++nt)
    #pragma unroll
    for (int r = 0; r < 4; ++r)
      feat[(size_t)(qbase + quad*4 + r)*128 + 64 + nt*16 + col] = o_acc[nt][r]*inv[r];
}

// ---------------------------------------------------------------------------
// MFMA forecast: out[16rows][24] = feat[16x128]@Wf^T + bf per wave.
__global__ __launch_bounds__(256) void forecast_kernel(
    const float* __restrict__ feat, const float* __restrict__ Wf,
    const float* __restrict__ bf, float* __restrict__ out)
{
  __shared__ short Wfr[8*512];         // 8 KB B-frags
  __shared__ float bl[32];

  const int tid  = threadIdx.x;
  const int lane = tid & 63;
  const int wv   = tid >> 6;
  const int quad = lane >> 4;
  const int col  = lane & 15;
  const int rowb = blockIdx.x*64 + wv*16;

  #pragma unroll
  for (int i = 0; i < 2; ++i) {
    int p = i*256 + tid;               // 512 (frag,lane) entries
    int f = p >> 6, l = p & 63;
    int kc = f >> 1, nt = f & 1;
    int lq = l >> 4, lc = l & 15;
    int n = nt*16 + lc;
    bf16x8 v;
    #pragma unroll
    for (int j = 0; j < 8; ++j) v[j] = 0;
    if (n < 24) {
      const float* src = Wf + (size_t)n*128 + kc*32 + lq*8;
      #pragma unroll
      for (int j = 0; j < 8; ++j) v[j] = (short)f2bf(src[j]);
    }
    *(bf16x8*)(Wfr + f*512 + l*8) = v;
  }
  if (tid < 32) bl[tid] = (tid < 24) ? bf[tid] : 0.f;
  __syncthreads();

  // A-frags: my row (rowb+col), 4 k32 chunks
  bf16x8 af[4];
  const float* fr = feat + (size_t)(rowb + col)*128;
  #pragma unroll
  for (int kc = 0; kc < 4; ++kc) {
    float4 f0 = *(const float4*)(fr + kc*32 + quad*8);
    float4 f1 = *(const float4*)(fr + kc*32 + quad*8 + 4);
    af[kc][0]=(short)f2bf(f0.x); af[kc][1]=(short)f2bf(f0.y);
    af[kc][2]=(short)f2bf(f0.z); af[kc][3]=(short)f2bf(f0.w);
    af[kc][4]=(short)f2bf(f1.x); af[kc][5]=(short)f2bf(f1.y);
    af[kc][6]=(short)f2bf(f1.z); af[kc][7]=(short)f2bf(f1.w);
  }

  f32x4 acc[2];
  #pragma unroll
  for (int nt = 0; nt < 2; ++nt) {
    float bb = bl[nt*16 + col];
    acc[nt][0] = bb; acc[nt][1] = bb; acc[nt][2] = bb; acc[nt][3] = bb;
  }
  #pragma unroll
  for (int kc = 0; kc < 4; ++kc) {
    #pragma unroll
    for (int nt = 0; nt < 2; ++nt) {
      bf16x8 b = *(const bf16x8*)(Wfr + (kc*2+nt)*512 + lane*8);
      acc[nt] = __builtin_amdgcn_mfma_f32_16x16x32_bf16(af[kc], b, acc[nt], 0,0,0);
    }
  }

  #pragma unroll
  for (int nt = 0; nt < 2; ++nt) {
    int n = nt*16 + col;
    if (n < 24) {
      #pragma unroll
      for (int r = 0; r < 4; ++r)
        out[(size_t)(rowb + quad*4 + r)*24 + n] = acc[nt][r];
    }
  }
}

// ---------------------------------------------------------------------------
extern "C" void kernel_launch(void* const* d_in, const int* in_sizes, int n_in,
                              void* d_out, int out_size, void* d_ws, size_t ws_size,
                              hipStream_t stream)
{
  const float* obs = (const float*)d_in[0];
  const int*   pm  = (const int*)  d_in[1];
  const float* nhm = (const float*)d_in[2];
  const float* Wih = (const float*)d_in[3];
  const float* Whh = (const float*)d_in[4];
  const float* bih = (const float*)d_in[5];
  const float* bhh = (const float*)d_in[6];
  const float* W1  = (const float*)d_in[7];
  const float* b1  = (const float*)d_in[8];
  const float* W2  = (const float*)d_in[9];
  const float* b2  = (const float*)d_in[10];
  const float* Wh  = (const float*)d_in[11];
  const float* bh  = (const float*)d_in[12];
  const float* Wq  = (const float*)d_in[13];
  const float* bq  = (const float*)d_in[14];
  const float* Wk  = (const float*)d_in[15];
  const float* bk  = (const float*)d_in[16];
  const float* Wv  = (const float*)d_in[17];
  const float* bv  = (const float*)d_in[18];
  const float* Wf  = (const float*)d_in[19];
  const float* bf  = (const float*)d_in[20];

  float* out  = (float*)d_out;                 // forecast: 65536*24
  float* feat = out + (size_t)M_*24;           // feat:     65536*128

  // workspace: he(8MB) | qb(8MB) | kb(8MB) | vt(8MB) | bitmask(4.2MB)
  char* ws = (char*)d_ws;
  unsigned short* he  = (unsigned short*)(ws);
  unsigned short* qbf = (unsigned short*)(ws + (size_t) 8*1024*1024);
  unsigned short* kbf = (unsigned short*)(ws + (size_t)16*1024*1024);
  unsigned short* vtb = (unsigned short*)(ws + (size_t)24*1024*1024);
  uint32_t*       bmw = (uint32_t*)      (ws + (size_t)32*1024*1024);

  const int nmask = B_*N_*N_;
  maskpack_kernel<<<nmask/256, 256, 0, stream>>>(pm, bmw, nmask);
  lstm_kernel<<<M_/64, 256, 0, stream>>>(obs, nhm, Wih, Whh, bih, bhh, he);
  mlp_kernel<<<M_/64, 256, 0, stream>>>(he, W1,b1, W2,b2, Wh,bh, Wq,bq, Wk,bk, Wv,bv,
                                        qbf, kbf, vtb, feat);
  attn_kernel<<<M_/64, 256, 0, stream>>>(qbf, kbf, vtb, bmw, feat);
  forecast_kernel<<<M_/64, 256, 0, stream>>>(feat, Wf, bf, out);
}